// Round 15
// baseline (1327.915 us; speedup 1.0000x reference)
//
#include <hip/hip_runtime.h>

#define DEV __device__ __forceinline__

typedef float f2 __attribute__((ext_vector_type(2)));

// ---------- packed fp32 helpers (VOP3P) ----------

DEV f2 pkfma(f2 a, f2 b, f2 c) {  // c = a*b + c (acc form)
  asm("v_pk_fma_f32 %0, %1, %2, %0" : "+v"(c) : "v"(a), "v"(b));
  return c;
}
DEV f2 pkfma3(f2 a, f2 b, f2 c) {  // d = a*b + c (3-addr form)
  f2 d;
  asm("v_pk_fma_f32 %0, %1, %2, %3" : "=v"(d) : "v"(a), "v"(b), "v"(c));
  return d;
}
DEV f2 pkadd(f2 a, f2 b) {
  f2 d;
  asm("v_pk_add_f32 %0, %1, %2" : "=v"(d) : "v"(a), "v"(b));
  return d;
}

// ---------- cross-lane helpers ----------

template <int CTRL>
DEV float dppf(float x) {
  return __int_as_float(__builtin_amdgcn_update_dpp(
      0, __float_as_int(x), CTRL, 0xF, 0xF, true));
}

// Butterfly sum within each 32-lane half; result broadcast to the half.
DEV float wsum32(float v) {
  v += dppf<0xB1>(v);
  v += dppf<0x4E>(v);
  v += dppf<0x141>(v);
  v += dppf<0x140>(v);
#if __has_builtin(__builtin_amdgcn_permlane16_swap)
  {
    auto p = __builtin_amdgcn_permlane16_swap(
        __float_as_uint(v), __float_as_uint(v), false, false);
    v = __uint_as_float(p[0]) + __uint_as_float(p[1]);
  }
#else
  v += __shfl_xor(v, 16, 64);
#endif
  return v;
}

// v[l] + v[l^32]
DEV float halfsum(float v) {
#if __has_builtin(__builtin_amdgcn_permlane32_swap)
  auto p = __builtin_amdgcn_permlane32_swap(
      __float_as_uint(v), __float_as_uint(v), false, false);
  return __uint_as_float(p[0]) + __uint_as_float(p[1]);
#else
  return v + __shfl_xor(v, 32, 64);
#endif
}

#define SLEN 1024
#define NH 8
#define DH 32
#define HSTRIDE 2048  // floats per timestep (B*NH*DH)
#define CPB 8         // chains per block (8 chains x 2 waves = 16 waves/block)

// ---------- phase 1: x = softmax32(h), staged into d_out ----------

__global__ __launch_bounds__(256)
void srwm_xsm(const float* __restrict__ h, float* __restrict__ x) {
  int i = blockIdx.x * 256 + threadIdx.x;
  float e = __expf(h[i]);
  x[i] = __fdividef(e, wsum32(e));
}

// ---------- phase 2: the scan. 8 chains per 1024-thread block. ----------
// Each chain = 2 waves: wave 0 owns Wy+Wq; wave 1 owns Wk+wb^T (f2 col-pairs).
// Lane (r=lane&31, c0) holds cols c0..c0+15 of row r.
//
// R14 post-mortem: step = ~578cy issue + ~500cy dependency/barrier stall,
// with exactly ONE wave per SIMD (no stall coverage). This round packs 8
// independent chains into one block -> 16 waves -> 4 waves/SIMD. The shared
// s_barrier couples the (symmetric) chains; each SIMD now has 4 independent
// instruction streams, so one chain's serial softmax chain is covered by the
// other chains' issue. Region math/schedule byte-identical to R14; only the
// chain->block packing and LDS base (chain*144 floats) change.
//
// Shared layout per chain: slot P stride 72 floats: q[32]@0, k[32]@32, B[4]@64.

#define BARRIER()                                        \
  do {                                                   \
    __builtin_amdgcn_sched_barrier(0);                   \
    asm volatile("s_waitcnt lgkmcnt(0)");                \
    __builtin_amdgcn_sched_barrier(0);                   \
    __builtin_amdgcn_s_barrier();                        \
    __builtin_amdgcn_sched_barrier(0);                   \
  } while (0)

// load 16 floats at PTR into f2 DST[8] via 4x float4
#define LDX4(DST, PTR)                                                        \
  { _Pragma("unroll") for (int i_ = 0; i_ < 4; ++i_) {                        \
      float4 a_ = *(const float4*)((PTR) + 4 * i_);                           \
      DST[2*i_]   = f2{a_.x, a_.y};                                           \
      DST[2*i_+1] = f2{a_.z, a_.w}; } }

#define REGION(P, QV, KV, BP, QN, KN, BPN, XS, XP, XPF, YPTR)                 \
  {                                                                           \
    /* ---- PRE: on-path compute ---- */                                      \
    f2 dv[8];                                                                 \
    _Pragma("unroll") for (int j = 0; j < 8; ++j)                             \
      dv[j] = pkfma3(KV[j], mone, QV[j]);       /* q - k */                   \
    f2 daA={0.f,0.f}, daB={0.f,0.f}, dbA={0.f,0.f}, dbB={0.f,0.f};            \
    f2 sA={0.f,0.f}, sB={0.f,0.f};                                            \
    _Pragma("unroll") for (int j = 0; j < 8; j += 2) {                        \
      daA = pkfma(Wa2[j],   dv[j],   daA);                                    \
      daB = pkfma(Wa2[j+1], dv[j+1], daB);                                    \
      dbA = pkfma(Wb2[j],   dv[j],   dbA);                                    \
      dbB = pkfma(Wb2[j+1], dv[j+1], dbB);                                    \
      sA  = pkfma(KV[j],    XS[j],   sA);                                     \
      sB  = pkfma(KV[j+1],  XS[j+1], sB);                                     \
    }                                                                         \
    f2 dac = pkadd(daA, daB), dbc = pkadd(dbA, dbB), sc = pkadd(sA, sB);      \
    float da = halfsum(dac.x + dac.y);                                        \
    float db = halfsum(dbc.x + dbc.y);                                        \
    float sv = halfsum(sc.x + sc.y);                                          \
    float ua = BP.x * da, ub = BP.y * db;                                     \
    float aA = fmaf(ua, sv, preAa);                                           \
    float aB = fmaf(ub, sv, preAb);                                           \
    if (w == 0) {                                                             \
      if (lane < DH) *(YPTR) = aA;  /* y_T */                                 \
      float e = __expf(aB);                                                   \
      shb[chbase + (P)*72 + r] = __fdividef(e, wsum32(e));        /* q_T */   \
    } else {                                                                  \
      float e = __expf(aA);                                                   \
      shb[chbase + (P)*72 + 32 + r] = __fdividef(e, wsum32(e));   /* k_T */   \
      float sg = __fdividef(1.f, 1.f + __expf(-aB));                          \
      if (lane < 4) shb[chbase + (P)*72 + 64 + lane] = sg;        /* B_T */   \
    }                                                                         \
    BARRIER();                                                                \
    /* ---- POST: reads + register work ---- */                               \
    LDX4(QN, &shb[chbase + (P)*72 + c0]);                                     \
    LDX4(KN, &shb[chbase + (P)*72 + 32 + c0]);                                \
    BPN = *(const float2*)&shb[chbase + (P)*72 + 64 + 2*w];                   \
    f2 uua = f2{ua, ua}, uub = f2{ub, ub};                                    \
    _Pragma("unroll") for (int j = 0; j < 8; ++j) {                           \
      Wa2[j] = pkfma(uua, KV[j], Wa2[j]);                                     \
      Wb2[j] = pkfma(uub, KV[j], Wb2[j]);                                     \
    }                                                                         \
    LDX4(XS, XPF);                                /* prefetch x_{T+2} */      \
    f2 paA={0.f,0.f}, paB={0.f,0.f}, pbA={0.f,0.f}, pbB={0.f,0.f};            \
    _Pragma("unroll") for (int j = 0; j < 8; j += 2) {                        \
      paA = pkfma(Wa2[j],   XP[j],   paA);                                    \
      paB = pkfma(Wa2[j+1], XP[j+1], paB);                                    \
      pbA = pkfma(Wb2[j],   XP[j],   pbA);                                    \
      pbB = pkfma(Wb2[j+1], XP[j+1], pbB);                                    \
    }                                                                         \
    f2 pac = pkadd(paA, paB), pbc = pkadd(pbA, pbB);                          \
    preAa = halfsum(pac.x + pac.y);                                           \
    preAb = halfsum(pbc.x + pbc.y);                                           \
  }

__global__ __launch_bounds__(1024, 1)
void srwm_scan(const float* __restrict__ Wy0, const float* __restrict__ Wq0,
               const float* __restrict__ Wk0, const float* __restrict__ wb0,
               float* xy) {
  __align__(16) __shared__ float shb[CPB * 144];  // per chain: [P][72]

  const int tid   = threadIdx.x;
  const int chain = tid >> 7;          // 0..7
  const int w     = (tid >> 6) & 1;    // wave within chain: 0 (Wy,Wq) 1 (Wk,wb)
  const int lane  = tid & 63;
  const int r     = lane & 31;
  const int c0    = (lane >> 5) * 16;
  const int chbase = chain * 144;

  const int bh = blockIdx.x * CPB + chain;  // 0..63
  const int hd = bh & 7;

  const f2 mone = f2{-1.f, -1.f};

  // ---- load this wave's two matrices as f2 column-pairs ----
  f2 Wa2[8], Wb2[8];
  if (w == 0) {
    const float* pa = Wy0 + (hd * DH + r) * DH + c0;
    const float* pb = Wq0 + (hd * DH + r) * DH + c0;
    LDX4(Wa2, pa);
    LDX4(Wb2, pb);
  } else {
    const float* pa = Wk0 + (hd * DH + r) * DH + c0;
    LDX4(Wa2, pa);
    const int kk = r & 3;
#pragma unroll
    for (int j = 0; j < 8; ++j)
      Wb2[j] = f2{wb0[(hd * DH + c0 + 2*j) * 4 + kk],
                  wb0[(hd * DH + c0 + 2*j + 1) * 4 + kk]};
  }

  float* xb = xy + bh * DH;  // x/y for this (b,h): element [t*HSTRIDE + j]

  // ---- prologue: X0 <- x_0, X1 <- x_1; q_{-1}=k_{-1}=0, B_{-1}=0;
  //      preA = W_0 x_0 (u_{-1}=0) ----
  f2 X0[8], X1[8];
  LDX4(X0, xb + c0);
  LDX4(X1, xb + HSTRIDE + c0);

  float preAa, preAb;
  {
    f2 paA={0.f,0.f}, paB={0.f,0.f}, pbA={0.f,0.f}, pbB={0.f,0.f};
#pragma unroll
    for (int j = 0; j < 8; j += 2) {
      paA = pkfma(Wa2[j],   X0[j],   paA);
      paB = pkfma(Wa2[j+1], X0[j+1], paB);
      pbA = pkfma(Wb2[j],   X0[j],   pbA);
      pbB = pkfma(Wb2[j+1], X0[j+1], pbB);
    }
    f2 pac = pkadd(paA, paB), pbc = pkadd(pbA, pbB);
    preAa = halfsum(pac.x + pac.y);
    preAb = halfsum(pbc.x + pbc.y);
  }

  f2 QA[8], KA[8], QB[8], KB[8];
  const f2 z2 = f2{0.f, 0.f};
#pragma unroll
  for (int j = 0; j < 8; ++j) { QA[j] = z2; KA[j] = z2; }
  float2 BPA = {0.f, 0.f}, BPB = {0.f, 0.f};

  __syncthreads();

  // hot loop: strength-reduced pointers, no clamp (tail peeled)
  const float* xpf = xb + 2 * HSTRIDE + c0;  // x_{t+2} for region t
  float*       yst = xb + lane;              // y_t (w0, lane<32)

  for (int t = 0; t < SLEN - 4; t += 2) {
    REGION(0, QA, KA, BPA, QB, KB, BPB, X0, X1, xpf,           yst);
    REGION(1, QB, KB, BPB, QA, KA, BPA, X1, X0, xpf + HSTRIDE, yst + HSTRIDE);
    xpf += 2 * HSTRIDE;
    yst += 2 * HSTRIDE;
  }
  // tail: t = 1020..1023, prefetch clamped to x_{SLEN-1}
  {
    const float* xlast = xb + (size_t)(SLEN - 1) * HSTRIDE + c0;
    REGION(0, QA, KA, BPA, QB, KB, BPB, X0, X1, xlast - HSTRIDE, yst);
    REGION(1, QB, KB, BPB, QA, KA, BPA, X1, X0, xlast,           yst + HSTRIDE);
    yst += 2 * HSTRIDE;
    REGION(0, QA, KA, BPA, QB, KB, BPB, X0, X1, xlast, yst);
    REGION(1, QB, KB, BPB, QA, KA, BPA, X1, X0, xlast, yst + HSTRIDE);
  }
}

// ---------- phase 3: out = h + ys @ Wout^T  (in-place over ys==out) ----------

__global__ __launch_bounds__(256)
void srwm_proj(const float* __restrict__ h, const float* __restrict__ ys,
               const float* __restrict__ Wout, float* __restrict__ out) {
  __shared__ float ytile[32][256];  // 32 KB
  const int r0  = blockIdx.x * 32;
  const int tid = threadIdx.x;

  const float4* src = (const float4*)(ys + (size_t)r0 * 256);
  float4*       dst = (float4*)(&ytile[0][0]);
#pragma unroll
  for (int i = 0; i < 8; ++i) dst[tid + i * 256] = src[tid + i * 256];
  __syncthreads();

  float acc[32];
#pragma unroll
  for (int m = 0; m < 32; ++m) acc[m] = 0.f;

  const float* wrow = Wout + (size_t)tid * 256;
  for (int k = 0; k < 256; k += 4) {
    float4 wv = *(const float4*)(wrow + k);
#pragma unroll
    for (int m = 0; m < 32; ++m) {
      float4 y4 = *(const float4*)(&ytile[m][k]);
      acc[m] = fmaf(wv.x, y4.x,
               fmaf(wv.y, y4.y,
               fmaf(wv.z, y4.z,
               fmaf(wv.w, y4.w, acc[m]))));
    }
  }

#pragma unroll
  for (int m = 0; m < 32; ++m) {
    int row = r0 + m;
    out[(size_t)row * 256 + tid] = h[(size_t)row * 256 + tid] + acc[m];
  }
}

// ---------- launcher ----------

extern "C" void kernel_launch(void* const* d_in, const int* in_sizes, int n_in,
                              void* d_out, int out_size, void* d_ws, size_t ws_size,
                              hipStream_t stream) {
  const float* h    = (const float*)d_in[0];
  const float* Wy0  = (const float*)d_in[1];
  const float* Wq0  = (const float*)d_in[2];
  const float* Wk0  = (const float*)d_in[3];
  const float* wb0  = (const float*)d_in[4];
  const float* Wout = (const float*)d_in[5];
  float* out = (float*)d_out;

  // d_out triple duty: x (phase1) -> progressively overwritten by y (phase2)
  // -> final output (phase3, in-place via LDS tile).
  srwm_xsm <<<SLEN * HSTRIDE / 256, 256, 0, stream>>>(h, out);
  srwm_scan<<<64 / CPB, 128 * CPB, 0, stream>>>(Wy0, Wq0, Wk0, wb0, out);
  srwm_proj<<<256, 256, 0, stream>>>(h, out, Wout, out);
}

// Round 16
// 637.368 us; speedup vs baseline: 2.0834x; 2.0834x over previous
//
#include <hip/hip_runtime.h>

#define DEV __device__ __forceinline__

typedef float f2 __attribute__((ext_vector_type(2)));

// ---------- packed fp32 helpers (VOP3P) ----------

DEV f2 pkfma(f2 a, f2 b, f2 c) {  // c = a*b + c (acc form)
  asm("v_pk_fma_f32 %0, %1, %2, %0" : "+v"(c) : "v"(a), "v"(b));
  return c;
}
DEV f2 pkfma3(f2 a, f2 b, f2 c) {  // d = a*b + c (3-addr form)
  f2 d;
  asm("v_pk_fma_f32 %0, %1, %2, %3" : "=v"(d) : "v"(a), "v"(b), "v"(c));
  return d;
}
DEV f2 pkadd(f2 a, f2 b) {
  f2 d;
  asm("v_pk_add_f32 %0, %1, %2" : "=v"(d) : "v"(a), "v"(b));
  return d;
}
DEV f2 pkmul(f2 a, f2 b) {
  f2 d;
  asm("v_pk_mul_f32 %0, %1, %2" : "=v"(d) : "v"(a), "v"(b));
  return d;
}

// ---------- cross-lane helpers ----------

template <int CTRL>
DEV float dppf(float x) {
  return __int_as_float(__builtin_amdgcn_update_dpp(
      0, __float_as_int(x), CTRL, 0xF, 0xF, true));
}

// Butterfly sum within each 32-lane half; result broadcast to the half.
DEV float wsum32(float v) {
  v += dppf<0xB1>(v);
  v += dppf<0x4E>(v);
  v += dppf<0x141>(v);
  v += dppf<0x140>(v);
#if __has_builtin(__builtin_amdgcn_permlane16_swap)
  {
    auto p = __builtin_amdgcn_permlane16_swap(
        __float_as_uint(v), __float_as_uint(v), false, false);
    v = __uint_as_float(p[0]) + __uint_as_float(p[1]);
  }
#else
  v += __shfl_xor(v, 16, 64);
#endif
  return v;
}

// v[l] + v[l^32]
DEV float halfsum(float v) {
#if __has_builtin(__builtin_amdgcn_permlane32_swap)
  auto p = __builtin_amdgcn_permlane32_swap(
      __float_as_uint(v), __float_as_uint(v), false, false);
  return __uint_as_float(p[0]) + __uint_as_float(p[1]);
#else
  return v + __shfl_xor(v, 32, 64);
#endif
}

#define SLEN 1024
#define NH 8
#define DH 32
#define HSTRIDE 2048  // floats per timestep (B*NH*DH)

// ---------- phase 1: x = softmax32(h), staged into d_out ----------

__global__ __launch_bounds__(256)
void srwm_xsm(const float* __restrict__ h, float* __restrict__ x) {
  int i = blockIdx.x * 256 + threadIdx.x;
  float e = __expf(h[i]);
  x[i] = __fdividef(e, wsum32(e));
}

// ---------- phase 2: the scan. One block (TWO waves) per (b,h). ----------
// Wave 0 owns Wy+Wq; wave 1 owns Wk+wb^T (f2 col-pairs). Lane (r=lane&31,
// c0) holds cols c0..c0+15 of row r.
//
// R14 base + two serial-tail cuts (R15 lesson: only single-chain step
// latency matters — co-residency is irrelevant with 64 chains on 256 CUs):
//  (1) W-update moved PRE-barrier (register-only; fills the write-drain gap)
//  (2) DENORMALIZED exchange: producers write raw exp(a) and raw beta
//      pre-activations -> pre-barrier chain loses wsum32+fdiv+sigmoid.
//      Consumers rebuild in POST (under read/barrier slack): vector sums ->
//      rq,rk = 1/S; sigmoid on own 2 beta scalars. PRE folds: dv = rq*eq -
//      rk*ek (+8 pk), sv *= rk, u' = u*rk (scalar). Algebra verified in R11.
//
// Shared layout, slot P stride 72 floats: eq[32]@0, ek[32]@32, aB[4]@64.

#define BARRIER()                                        \
  do {                                                   \
    __builtin_amdgcn_sched_barrier(0);                   \
    asm volatile("s_waitcnt lgkmcnt(0)");                \
    __builtin_amdgcn_sched_barrier(0);                   \
    __builtin_amdgcn_s_barrier();                        \
    __builtin_amdgcn_sched_barrier(0);                   \
  } while (0)

// load 16 floats at PTR into f2 DST[8] via 4x float4
#define LDX4(DST, PTR)                                                        \
  { _Pragma("unroll") for (int i_ = 0; i_ < 4; ++i_) {                        \
      float4 a_ = *(const float4*)((PTR) + 4 * i_);                           \
      DST[2*i_]   = f2{a_.x, a_.y};                                           \
      DST[2*i_+1] = f2{a_.z, a_.w}; } }

#define REGION(P, QV, KV, BP, RQ, RK, QN, KN, BPN, RQN, RKN, XS, XP, XPF, YPTR) \
  {                                                                           \
    /* ---- PRE: on-path compute (QV=raw eq, KV=raw ek) ---- */               \
    f2 rqv = f2{RQ, RQ}, mrkv = f2{-RK, -RK};                                 \
    f2 dv[8];                                                                 \
    _Pragma("unroll") for (int j = 0; j < 8; ++j)                             \
      dv[j] = pkfma3(QV[j], rqv, pkmul(KV[j], mrkv));  /* q - k */            \
    f2 daA={0.f,0.f}, daB={0.f,0.f}, dbA={0.f,0.f}, dbB={0.f,0.f};            \
    f2 sA={0.f,0.f}, sB={0.f,0.f};                                            \
    _Pragma("unroll") for (int j = 0; j < 8; j += 2) {                        \
      daA = pkfma(Wa2[j],   dv[j],   daA);                                    \
      daB = pkfma(Wa2[j+1], dv[j+1], daB);                                    \
      dbA = pkfma(Wb2[j],   dv[j],   dbA);                                    \
      dbB = pkfma(Wb2[j+1], dv[j+1], dbB);                                    \
      sA  = pkfma(KV[j],    XS[j],   sA);                                     \
      sB  = pkfma(KV[j+1],  XS[j+1], sB);                                     \
    }                                                                         \
    f2 dac = pkadd(daA, daB), dbc = pkadd(dbA, dbB), sc = pkadd(sA, sB);      \
    float da = halfsum(dac.x + dac.y);                                        \
    float db = halfsum(dbc.x + dbc.y);                                        \
    float sv = halfsum(sc.x + sc.y) * RK;   /* k.x = rk*(ek.x) */             \
    float ua = BP.x * da, ub = BP.y * db;                                     \
    float aA = fmaf(ua, sv, preAa);                                           \
    float aB = fmaf(ub, sv, preAb);                                           \
    /* ---- ship RAW values (short serial tail) ---- */                       \
    if (w == 0) {                                                             \
      if (lane < DH) *(YPTR) = aA;                      /* y_T */             \
      shb[(P)*72 + r] = __expf(aB);                     /* raw eq_T */        \
    } else {                                                                  \
      shb[(P)*72 + 32 + r] = __expf(aA);                /* raw ek_T */        \
      if (lane < 4) shb[(P)*72 + 64 + lane] = aB;       /* raw beta preact */ \
    }                                                                         \
    /* ---- W <- W_T pre-barrier (fills write-drain gap); k = rk*ek ---- */   \
    float uaK = ua * RK, ubK = ub * RK;                                       \
    f2 uua = f2{uaK, uaK}, uub = f2{ubK, ubK};                                \
    _Pragma("unroll") for (int j = 0; j < 8; ++j) {                           \
      Wa2[j] = pkfma(uua, KV[j], Wa2[j]);                                     \
      Wb2[j] = pkfma(uub, KV[j], Wb2[j]);                                     \
    }                                                                         \
    BARRIER();                                                                \
    /* ---- POST: reads + normalization rebuild + preA ---- */                \
    LDX4(QN, &shb[(P)*72 + c0]);                                              \
    LDX4(KN, &shb[(P)*72 + 32 + c0]);                                         \
    float2 braw = *(const float2*)&shb[(P)*72 + 64 + 2*w];                    \
    { f2 sq = QN[0], sk = KN[0];                                              \
      _Pragma("unroll") for (int j = 1; j < 8; ++j) {                         \
        sq = pkadd(sq, QN[j]); sk = pkadd(sk, KN[j]);                         \
      }                                                                       \
      RQN = __fdividef(1.f, halfsum(sq.x + sq.y));                            \
      RKN = __fdividef(1.f, halfsum(sk.x + sk.y)); }                          \
    BPN.x = __fdividef(1.f, 1.f + __expf(-braw.x));                           \
    BPN.y = __fdividef(1.f, 1.f + __expf(-braw.y));                           \
    LDX4(XS, XPF);                                /* prefetch x_{T+2} */      \
    f2 paA={0.f,0.f}, paB={0.f,0.f}, pbA={0.f,0.f}, pbB={0.f,0.f};            \
    _Pragma("unroll") for (int j = 0; j < 8; j += 2) {                        \
      paA = pkfma(Wa2[j],   XP[j],   paA);                                    \
      paB = pkfma(Wa2[j+1], XP[j+1], paB);                                    \
      pbA = pkfma(Wb2[j],   XP[j],   pbA);                                    \
      pbB = pkfma(Wb2[j+1], XP[j+1], pbB);                                    \
    }                                                                         \
    f2 pac = pkadd(paA, paB), pbc = pkadd(pbA, pbB);                          \
    preAa = halfsum(pac.x + pac.y);                                           \
    preAb = halfsum(pbc.x + pbc.y);                                           \
  }

__global__ __launch_bounds__(128, 1)
void srwm_scan(const float* __restrict__ Wy0, const float* __restrict__ Wq0,
               const float* __restrict__ Wk0, const float* __restrict__ wb0,
               float* xy) {
  __align__(16) __shared__ float shb[2 * 72];  // slot P: eq@0, ek@32, aB@64

  const int bh   = blockIdx.x;        // 0..63
  const int hd   = bh & 7;
  const int w    = threadIdx.x >> 6;  // wave: 0 (Wy,Wq) or 1 (Wk,wb^T)
  const int lane = threadIdx.x & 63;
  const int r    = lane & 31;
  const int c0   = (lane >> 5) * 16;

  // ---- load this wave's two matrices as f2 column-pairs ----
  f2 Wa2[8], Wb2[8];
  if (w == 0) {
    const float* pa = Wy0 + (hd * DH + r) * DH + c0;
    const float* pb = Wq0 + (hd * DH + r) * DH + c0;
    LDX4(Wa2, pa);
    LDX4(Wb2, pb);
  } else {
    const float* pa = Wk0 + (hd * DH + r) * DH + c0;
    LDX4(Wa2, pa);
    const int kk = r & 3;
#pragma unroll
    for (int j = 0; j < 8; ++j)
      Wb2[j] = f2{wb0[(hd * DH + c0 + 2*j) * 4 + kk],
                  wb0[(hd * DH + c0 + 2*j + 1) * 4 + kk]};
  }

  float* xb = xy + bh * DH;  // x/y for this (b,h): element [t*HSTRIDE + j]

  // ---- prologue: X0 <- x_0, X1 <- x_1; raw eq_{-1}=ek_{-1}=1 (S=32,
  //      dv=0), B_{-1}=0 (sigmoided regs); preA = W_0 x_0 (u_{-1}=0) ----
  f2 X0[8], X1[8];
  LDX4(X0, xb + c0);
  LDX4(X1, xb + HSTRIDE + c0);

  float preAa, preAb;
  {
    f2 paA={0.f,0.f}, paB={0.f,0.f}, pbA={0.f,0.f}, pbB={0.f,0.f};
#pragma unroll
    for (int j = 0; j < 8; j += 2) {
      paA = pkfma(Wa2[j],   X0[j],   paA);
      paB = pkfma(Wa2[j+1], X0[j+1], paB);
      pbA = pkfma(Wb2[j],   X0[j],   pbA);
      pbB = pkfma(Wb2[j+1], X0[j+1], pbB);
    }
    f2 pac = pkadd(paA, paB), pbc = pkadd(pbA, pbB);
    preAa = halfsum(pac.x + pac.y);
    preAb = halfsum(pbc.x + pbc.y);
  }

  f2 QA[8], KA[8], QB[8], KB[8];
  const f2 one2 = f2{1.f, 1.f};
#pragma unroll
  for (int j = 0; j < 8; ++j) { QA[j] = one2; KA[j] = one2; }
  float2 BPA = {0.f, 0.f}, BPB = {0.f, 0.f};  // sigmoided betas (0 -> u=0)
  float rqA = 1.f / 32.f, rkA = 1.f / 32.f, rqB = 1.f / 32.f, rkB = 1.f / 32.f;

  __syncthreads();

  // hot loop: strength-reduced pointers, no clamp (tail peeled)
  const float* xpf = xb + 2 * HSTRIDE + c0;  // x_{t+2} for region t
  float*       yst = xb + lane;              // y_t (w0, lane<32)

  for (int t = 0; t < SLEN - 4; t += 2) {
    REGION(0, QA, KA, BPA, rqA, rkA, QB, KB, BPB, rqB, rkB,
           X0, X1, xpf, yst);
    REGION(1, QB, KB, BPB, rqB, rkB, QA, KA, BPA, rqA, rkA,
           X1, X0, xpf + HSTRIDE, yst + HSTRIDE);
    xpf += 2 * HSTRIDE;
    yst += 2 * HSTRIDE;
  }
  // tail: t = 1020..1023, prefetch clamped to x_{SLEN-1}
  {
    const float* xlast = xb + (size_t)(SLEN - 1) * HSTRIDE + c0;
    REGION(0, QA, KA, BPA, rqA, rkA, QB, KB, BPB, rqB, rkB,
           X0, X1, xlast - HSTRIDE, yst);
    REGION(1, QB, KB, BPB, rqB, rkB, QA, KA, BPA, rqA, rkA,
           X1, X0, xlast, yst + HSTRIDE);
    yst += 2 * HSTRIDE;
    REGION(0, QA, KA, BPA, rqA, rkA, QB, KB, BPB, rqB, rkB,
           X0, X1, xlast, yst);
    REGION(1, QB, KB, BPB, rqB, rkB, QA, KA, BPA, rqA, rkA,
           X1, X0, xlast, yst + HSTRIDE);
  }
}

// ---------- phase 3: out = h + ys @ Wout^T  (in-place over ys==out) ----------

__global__ __launch_bounds__(256)
void srwm_proj(const float* __restrict__ h, const float* __restrict__ ys,
               const float* __restrict__ Wout, float* __restrict__ out) {
  __shared__ float ytile[32][256];  // 32 KB
  const int r0  = blockIdx.x * 32;
  const int tid = threadIdx.x;

  const float4* src = (const float4*)(ys + (size_t)r0 * 256);
  float4*       dst = (float4*)(&ytile[0][0]);
#pragma unroll
  for (int i = 0; i < 8; ++i) dst[tid + i * 256] = src[tid + i * 256];
  __syncthreads();

  float acc[32];
#pragma unroll
  for (int m = 0; m < 32; ++m) acc[m] = 0.f;

  const float* wrow = Wout + (size_t)tid * 256;
  for (int k = 0; k < 256; k += 4) {
    float4 wv = *(const float4*)(wrow + k);
#pragma unroll
    for (int m = 0; m < 32; ++m) {
      float4 y4 = *(const float4*)(&ytile[m][k]);
      acc[m] = fmaf(wv.x, y4.x,
               fmaf(wv.y, y4.y,
               fmaf(wv.z, y4.z,
               fmaf(wv.w, y4.w, acc[m]))));
    }
  }

#pragma unroll
  for (int m = 0; m < 32; ++m) {
    int row = r0 + m;
    out[(size_t)row * 256 + tid] = h[(size_t)row * 256 + tid] + acc[m];
  }
}

// ---------- launcher ----------

extern "C" void kernel_launch(void* const* d_in, const int* in_sizes, int n_in,
                              void* d_out, int out_size, void* d_ws, size_t ws_size,
                              hipStream_t stream) {
  const float* h    = (const float*)d_in[0];
  const float* Wy0  = (const float*)d_in[1];
  const float* Wq0  = (const float*)d_in[2];
  const float* Wk0  = (const float*)d_in[3];
  const float* wb0  = (const float*)d_in[4];
  const float* Wout = (const float*)d_in[5];
  float* out = (float*)d_out;

  // d_out triple duty: x (phase1) -> progressively overwritten by y (phase2)
  // -> final output (phase3, in-place via LDS tile).
  srwm_xsm <<<SLEN * HSTRIDE / 256, 256, 0, stream>>>(h, out);
  srwm_scan<<<64, 128, 0, stream>>>(Wy0, Wq0, Wk0, wb0, out);
  srwm_proj<<<256, 256, 0, stream>>>(h, out, Wout, out);
}

// Round 18
// 584.154 us; speedup vs baseline: 2.2732x; 1.0911x over previous
//
#include <hip/hip_runtime.h>

#define DEV __device__ __forceinline__

typedef float f2 __attribute__((ext_vector_type(2)));

// ---------- packed fp32 helpers (VOP3P) ----------

DEV f2 pkfma(f2 a, f2 b, f2 c) {  // c = a*b + c (acc form)
  asm("v_pk_fma_f32 %0, %1, %2, %0" : "+v"(c) : "v"(a), "v"(b));
  return c;
}
DEV f2 pkfma3(f2 a, f2 b, f2 c) {  // d = a*b + c (3-addr form)
  f2 d;
  asm("v_pk_fma_f32 %0, %1, %2, %3" : "=v"(d) : "v"(a), "v"(b), "v"(c));
  return d;
}
DEV f2 pkadd(f2 a, f2 b) {
  f2 d;
  asm("v_pk_add_f32 %0, %1, %2" : "=v"(d) : "v"(a), "v"(b));
  return d;
}

// ---------- cross-lane helpers ----------

template <int CTRL>
DEV float dppf(float x) {
  return __int_as_float(__builtin_amdgcn_update_dpp(
      0, __float_as_int(x), CTRL, 0xF, 0xF, true));
}

// Butterfly sum within each 32-lane half; result broadcast to the half.
DEV float wsum32(float v) {
  v += dppf<0xB1>(v);
  v += dppf<0x4E>(v);
  v += dppf<0x141>(v);
  v += dppf<0x140>(v);
#if __has_builtin(__builtin_amdgcn_permlane16_swap)
  {
    auto p = __builtin_amdgcn_permlane16_swap(
        __float_as_uint(v), __float_as_uint(v), false, false);
    v = __uint_as_float(p[0]) + __uint_as_float(p[1]);
  }
#else
  v += __shfl_xor(v, 16, 64);
#endif
  return v;
}

// v[l] + v[l^32]
DEV float halfsum(float v) {
#if __has_builtin(__builtin_amdgcn_permlane32_swap)
  auto p = __builtin_amdgcn_permlane32_swap(
      __float_as_uint(v), __float_as_uint(v), false, false);
  return __uint_as_float(p[0]) + __uint_as_float(p[1]);
#else
  return v + __shfl_xor(v, 32, 64);
#endif
}

#define SLEN 1024
#define NH 8
#define DH 32
#define HSTRIDE 2048  // floats per timestep (B*NH*DH)

// ---------- phase 1: x = softmax32(h), staged into d_out ----------

__global__ __launch_bounds__(256)
void srwm_xsm(const float* __restrict__ h, float* __restrict__ x) {
  int i = blockIdx.x * 256 + threadIdx.x;
  float e = __expf(h[i]);
  x[i] = __fdividef(e, wsum32(e));
}

// ---------- phase 2: the scan. One block (TWO waves) per (b,h). ----------
// Wave 0 owns Wy+Wq; wave 1 owns Wk+wb^T (f2 col-pairs). Lane (r=lane&31,
// c0) holds cols c0..c0+15 of row r.
//
// = R14 exactly (verified passing, 460us scan) + ONE safe change:
//   RAW-BETA SHIP: w1 writes the 4 raw beta preacts (drops its sigmoid
//   chain from the pre-barrier serial tail, balancing wave arrival);
//   each wave sigmoids its own 2 scalars in POST under the read-latency
//   window. Elementwise => identical math; both reads are post-barrier.
// R17 lesson: NO float4<->f2 type punning (strict-aliasing UB corrupted
// the asm-operand arrays under graph replay). All f2 marshaling stays the
// explicit R14 form.
//
// Shared layout, slot P stride 72 floats: q[32]@0, k[32]@32, braw[4]@64.

#define BARRIER()                                        \
  do {                                                   \
    __builtin_amdgcn_sched_barrier(0);                   \
    asm volatile("s_waitcnt lgkmcnt(0)");                \
    __builtin_amdgcn_sched_barrier(0);                   \
    __builtin_amdgcn_s_barrier();                        \
    __builtin_amdgcn_sched_barrier(0);                   \
  } while (0)

// load 16 floats at PTR into f2 DST[8] via 4x float4 (explicit repack)
#define LDX4(DST, PTR)                                                        \
  { _Pragma("unroll") for (int i_ = 0; i_ < 4; ++i_) {                        \
      float4 a_ = *(const float4*)((PTR) + 4 * i_);                           \
      DST[2*i_]   = f2{a_.x, a_.y};                                           \
      DST[2*i_+1] = f2{a_.z, a_.w}; } }

#define REGION(P, QV, KV, BP, QN, KN, BPN, XS, XP, XPF, YPTR)                 \
  {                                                                           \
    /* ---- PRE: on-path compute ---- */                                      \
    f2 dv[8];                                                                 \
    _Pragma("unroll") for (int j = 0; j < 8; ++j)                             \
      dv[j] = pkfma3(KV[j], mone, QV[j]);       /* q - k */                   \
    f2 daA={0.f,0.f}, daB={0.f,0.f}, dbA={0.f,0.f}, dbB={0.f,0.f};            \
    f2 sA={0.f,0.f}, sB={0.f,0.f};                                            \
    _Pragma("unroll") for (int j = 0; j < 8; j += 2) {                        \
      daA = pkfma(Wa2[j],   dv[j],   daA);                                    \
      daB = pkfma(Wa2[j+1], dv[j+1], daB);                                    \
      dbA = pkfma(Wb2[j],   dv[j],   dbA);                                    \
      dbB = pkfma(Wb2[j+1], dv[j+1], dbB);                                    \
      sA  = pkfma(KV[j],    XS[j],   sA);                                     \
      sB  = pkfma(KV[j+1],  XS[j+1], sB);                                     \
    }                                                                         \
    f2 dac = pkadd(daA, daB), dbc = pkadd(dbA, dbB), sc = pkadd(sA, sB);      \
    float da = halfsum(dac.x + dac.y);                                        \
    float db = halfsum(dbc.x + dbc.y);                                        \
    float sv = halfsum(sc.x + sc.y);                                          \
    float ua = BP.x * da, ub = BP.y * db;                                     \
    float aA = fmaf(ua, sv, preAa);                                           \
    float aB = fmaf(ub, sv, preAb);                                           \
    if (w == 0) {                                                             \
      if (lane < DH) *(YPTR) = aA;  /* y_T */                                 \
      float e = __expf(aB);                                                   \
      shb[(P)*72 + r] = __fdividef(e, wsum32(e));          /* q_T */          \
    } else {                                                                  \
      float e = __expf(aA);                                                   \
      shb[(P)*72 + 32 + r] = __fdividef(e, wsum32(e));     /* k_T */          \
      if (lane < 4) shb[(P)*72 + 64 + lane] = aB;          /* raw beta */     \
    }                                                                         \
    BARRIER();                                                                \
    /* ---- POST: reads + register work (update, sigmoid, prefetch, preA) */  \
    LDX4(QN, &shb[(P)*72 + c0]);                                              \
    LDX4(KN, &shb[(P)*72 + 32 + c0]);                                         \
    float2 braw = *(const float2*)&shb[(P)*72 + 64 + 2*w];                    \
    f2 uua = f2{ua, ua}, uub = f2{ub, ub};                                    \
    _Pragma("unroll") for (int j = 0; j < 8; ++j) {                           \
      Wa2[j] = pkfma(uua, KV[j], Wa2[j]);                                     \
      Wb2[j] = pkfma(uub, KV[j], Wb2[j]);                                     \
    }                                                                         \
    BPN.x = __fdividef(1.f, 1.f + __expf(-braw.x));                           \
    BPN.y = __fdividef(1.f, 1.f + __expf(-braw.y));                           \
    LDX4(XS, XPF);                                /* prefetch x_{T+2} */      \
    f2 paA={0.f,0.f}, paB={0.f,0.f}, pbA={0.f,0.f}, pbB={0.f,0.f};            \
    _Pragma("unroll") for (int j = 0; j < 8; j += 2) {                        \
      paA = pkfma(Wa2[j],   XP[j],   paA);                                    \
      paB = pkfma(Wa2[j+1], XP[j+1], paB);                                    \
      pbA = pkfma(Wb2[j],   XP[j],   pbA);                                    \
      pbB = pkfma(Wb2[j+1], XP[j+1], pbB);                                    \
    }                                                                         \
    f2 pac = pkadd(paA, paB), pbc = pkadd(pbA, pbB);                          \
    preAa = halfsum(pac.x + pac.y);                                           \
    preAb = halfsum(pbc.x + pbc.y);                                           \
  }

__global__ __launch_bounds__(128, 1)
void srwm_scan(const float* __restrict__ Wy0, const float* __restrict__ Wq0,
               const float* __restrict__ Wk0, const float* __restrict__ wb0,
               float* xy) {
  __align__(16) __shared__ float shb[2 * 72];  // slot P: q@0, k@32, braw@64

  const int bh   = blockIdx.x;        // 0..63
  const int hd   = bh & 7;
  const int w    = threadIdx.x >> 6;  // wave: 0 (Wy,Wq) or 1 (Wk,wb^T)
  const int lane = threadIdx.x & 63;
  const int r    = lane & 31;
  const int c0   = (lane >> 5) * 16;

  const f2 mone = f2{-1.f, -1.f};

  // ---- load this wave's two matrices as f2 column-pairs ----
  f2 Wa2[8], Wb2[8];
  if (w == 0) {
    const float* pa = Wy0 + (hd * DH + r) * DH + c0;
    const float* pb = Wq0 + (hd * DH + r) * DH + c0;
    LDX4(Wa2, pa);
    LDX4(Wb2, pb);
  } else {
    const float* pa = Wk0 + (hd * DH + r) * DH + c0;
    LDX4(Wa2, pa);
    const int kk = r & 3;
#pragma unroll
    for (int j = 0; j < 8; ++j)
      Wb2[j] = f2{wb0[(hd * DH + c0 + 2*j) * 4 + kk],
                  wb0[(hd * DH + c0 + 2*j + 1) * 4 + kk]};
  }

  float* xb = xy + bh * DH;  // x/y for this (b,h): element [t*HSTRIDE + j]

  // ---- prologue: X0 <- x_0, X1 <- x_1; q_{-1}=k_{-1}=0, B_{-1}=0;
  //      preA = W_0 x_0 (u_{-1}=0) ----
  f2 X0[8], X1[8];
  LDX4(X0, xb + c0);
  LDX4(X1, xb + HSTRIDE + c0);

  float preAa, preAb;
  {
    f2 paA={0.f,0.f}, paB={0.f,0.f}, pbA={0.f,0.f}, pbB={0.f,0.f};
#pragma unroll
    for (int j = 0; j < 8; j += 2) {
      paA = pkfma(Wa2[j],   X0[j],   paA);
      paB = pkfma(Wa2[j+1], X0[j+1], paB);
      pbA = pkfma(Wb2[j],   X0[j],   pbA);
      pbB = pkfma(Wb2[j+1], X0[j+1], pbB);
    }
    f2 pac = pkadd(paA, paB), pbc = pkadd(pbA, pbB);
    preAa = halfsum(pac.x + pac.y);
    preAb = halfsum(pbc.x + pbc.y);
  }

  f2 QA[8], KA[8], QB[8], KB[8];
  const f2 z2 = f2{0.f, 0.f};
#pragma unroll
  for (int j = 0; j < 8; ++j) { QA[j] = z2; KA[j] = z2; }
  float2 BPA = {0.f, 0.f}, BPB = {0.f, 0.f};  // sigmoided betas (0 -> u=0)

  __syncthreads();

  // hot loop: strength-reduced pointers, no clamp (tail peeled)
  const float* xpf = xb + 2 * HSTRIDE + c0;  // x_{t+2} for region t
  float*       yst = xb + lane;              // y_t (w0, lane<32)

  for (int t = 0; t < SLEN - 4; t += 2) {
    REGION(0, QA, KA, BPA, QB, KB, BPB, X0, X1, xpf,           yst);
    REGION(1, QB, KB, BPB, QA, KA, BPA, X1, X0, xpf + HSTRIDE, yst + HSTRIDE);
    xpf += 2 * HSTRIDE;
    yst += 2 * HSTRIDE;
  }
  // tail: t = 1020..1023, prefetch clamped to x_{SLEN-1}
  {
    const float* xlast = xb + (size_t)(SLEN - 1) * HSTRIDE + c0;
    REGION(0, QA, KA, BPA, QB, KB, BPB, X0, X1, xlast - HSTRIDE, yst);
    REGION(1, QB, KB, BPB, QA, KA, BPA, X1, X0, xlast,           yst + HSTRIDE);
    yst += 2 * HSTRIDE;
    REGION(0, QA, KA, BPA, QB, KB, BPB, X0, X1, xlast, yst);
    REGION(1, QB, KB, BPB, QA, KA, BPA, X1, X0, xlast, yst + HSTRIDE);
  }
}

// ---------- phase 3: out = h + ys @ Wout^T  (in-place over ys==out) ----------

__global__ __launch_bounds__(256)
void srwm_proj(const float* __restrict__ h, const float* __restrict__ ys,
               const float* __restrict__ Wout, float* __restrict__ out) {
  __shared__ float ytile[32][256];  // 32 KB
  const int r0  = blockIdx.x * 32;
  const int tid = threadIdx.x;

  const float4* src = (const float4*)(ys + (size_t)r0 * 256);
  float4*       dst = (float4*)(&ytile[0][0]);
#pragma unroll
  for (int i = 0; i < 8; ++i) dst[tid + i * 256] = src[tid + i * 256];
  __syncthreads();

  float acc[32];
#pragma unroll
  for (int m = 0; m < 32; ++m) acc[m] = 0.f;

  const float* wrow = Wout + (size_t)tid * 256;
  for (int k = 0; k < 256; k += 4) {
    float4 wv = *(const float4*)(wrow + k);
#pragma unroll
    for (int m = 0; m < 32; ++m) {
      float4 y4 = *(const float4*)(&ytile[m][k]);
      acc[m] = fmaf(wv.x, y4.x,
               fmaf(wv.y, y4.y,
               fmaf(wv.z, y4.z,
               fmaf(wv.w, y4.w, acc[m]))));
    }
  }

#pragma unroll
  for (int m = 0; m < 32; ++m) {
    int row = r0 + m;
    out[(size_t)row * 256 + tid] = h[(size_t)row * 256 + tid] + acc[m];
  }
}

// ---------- launcher ----------

extern "C" void kernel_launch(void* const* d_in, const int* in_sizes, int n_in,
                              void* d_out, int out_size, void* d_ws, size_t ws_size,
                              hipStream_t stream) {
  const float* h    = (const float*)d_in[0];
  const float* Wy0  = (const float*)d_in[1];
  const float* Wq0  = (const float*)d_in[2];
  const float* Wk0  = (const float*)d_in[3];
  const float* wb0  = (const float*)d_in[4];
  const float* Wout = (const float*)d_in[5];
  float* out = (float*)d_out;

  // d_out triple duty: x (phase1) -> progressively overwritten by y (phase2)
  // -> final output (phase3, in-place via LDS tile).
  srwm_xsm <<<SLEN * HSTRIDE / 256, 256, 0, stream>>>(h, out);
  srwm_scan<<<64, 128, 0, stream>>>(Wy0, Wq0, Wk0, wb0, out);
  srwm_proj<<<256, 256, 0, stream>>>(h, out, Wout, out);
}

// Round 19
// 528.315 us; speedup vs baseline: 2.5135x; 1.1057x over previous
//
#include <hip/hip_runtime.h>

#define DEV __device__ __forceinline__

typedef float f2 __attribute__((ext_vector_type(2)));

// ---------- packed fp32 helpers (VOP3P) ----------

DEV f2 pkfma(f2 a, f2 b, f2 c) {  // c = a*b + c (acc form)
  asm("v_pk_fma_f32 %0, %1, %2, %0" : "+v"(c) : "v"(a), "v"(b));
  return c;
}
DEV f2 pkfma3(f2 a, f2 b, f2 c) {  // d = a*b + c (3-addr form)
  f2 d;
  asm("v_pk_fma_f32 %0, %1, %2, %3" : "=v"(d) : "v"(a), "v"(b), "v"(c));
  return d;
}
DEV f2 pkadd(f2 a, f2 b) {
  f2 d;
  asm("v_pk_add_f32 %0, %1, %2" : "=v"(d) : "v"(a), "v"(b));
  return d;
}

// ---------- cross-lane helpers ----------

template <int CTRL>
DEV float dppf(float x) {
  return __int_as_float(__builtin_amdgcn_update_dpp(
      0, __float_as_int(x), CTRL, 0xF, 0xF, true));
}

// Butterfly sum within each 32-lane half; result broadcast to the half.
DEV float wsum32(float v) {
  v += dppf<0xB1>(v);
  v += dppf<0x4E>(v);
  v += dppf<0x141>(v);
  v += dppf<0x140>(v);
#if __has_builtin(__builtin_amdgcn_permlane16_swap)
  {
    auto p = __builtin_amdgcn_permlane16_swap(
        __float_as_uint(v), __float_as_uint(v), false, false);
    v = __uint_as_float(p[0]) + __uint_as_float(p[1]);
  }
#else
  v += __shfl_xor(v, 16, 64);
#endif
  return v;
}

// v[l] + v[l^32]
DEV float halfsum(float v) {
#if __has_builtin(__builtin_amdgcn_permlane32_swap)
  auto p = __builtin_amdgcn_permlane32_swap(
      __float_as_uint(v), __float_as_uint(v), false, false);
  return __uint_as_float(p[0]) + __uint_as_float(p[1]);
#else
  return v + __shfl_xor(v, 32, 64);
#endif
}

#define SLEN 1024
#define NH 8
#define DH 32
#define HSTRIDE 2048  // floats per timestep (B*NH*DH)

// ---------- phase 1: x = softmax32(h), staged into d_out ----------

__global__ __launch_bounds__(256)
void srwm_xsm(const float* __restrict__ h, float* __restrict__ x) {
  int i = blockIdx.x * 256 + threadIdx.x;
  float e = __expf(h[i]);
  x[i] = __fdividef(e, wsum32(e));
}

// ---------- phase 2: the scan. One block (TWO waves) per (b,h). ----------
// Wave 0 owns Wy+Wq; wave 1 owns Wk+wb^T (f2 col-pairs). Lane (r=lane&31,
// c0) holds cols c0..c0+15 of row r.
//
// = R14 exactly (verified best: 460us scan) + ONE change:
//   DIRECT f2 LOADS: LDX4 reads f2 pairs straight from memory
//   (8x ds_read_b64 / global_load_dwordx2) instead of float4 quads +
//   elementwise f2{x,y} repack (4x b128 + ~16 v_mov). Destination is
//   written through its declared type (no R17-style punning).
// R18 lesson: keep sigmoid in PRE (raw-beta ship regressed).
//
// Shared layout, slot P stride 72 floats: q[32]@0, k[32]@32, B[4]@64.

#define BARRIER()                                        \
  do {                                                   \
    __builtin_amdgcn_sched_barrier(0);                   \
    asm volatile("s_waitcnt lgkmcnt(0)");                \
    __builtin_amdgcn_sched_barrier(0);                   \
    __builtin_amdgcn_s_barrier();                        \
    __builtin_amdgcn_sched_barrier(0);                   \
  } while (0)

// load 16 floats at PTR directly into f2 DST[8] (no repack movs)
#define LDX4(DST, PTR)                                                        \
  { _Pragma("unroll") for (int i_ = 0; i_ < 8; ++i_)                          \
      DST[i_] = *(const f2*)((PTR) + 2 * i_); }

#define REGION(P, QV, KV, BP, QN, KN, BPN, XS, XP, XPF, YPTR)                 \
  {                                                                           \
    /* ---- PRE: on-path compute ---- */                                      \
    f2 dv[8];                                                                 \
    _Pragma("unroll") for (int j = 0; j < 8; ++j)                             \
      dv[j] = pkfma3(KV[j], mone, QV[j]);       /* q - k */                   \
    f2 daA={0.f,0.f}, daB={0.f,0.f}, dbA={0.f,0.f}, dbB={0.f,0.f};            \
    f2 sA={0.f,0.f}, sB={0.f,0.f};                                            \
    _Pragma("unroll") for (int j = 0; j < 8; j += 2) {                        \
      daA = pkfma(Wa2[j],   dv[j],   daA);                                    \
      daB = pkfma(Wa2[j+1], dv[j+1], daB);                                    \
      dbA = pkfma(Wb2[j],   dv[j],   dbA);                                    \
      dbB = pkfma(Wb2[j+1], dv[j+1], dbB);                                    \
      sA  = pkfma(KV[j],    XS[j],   sA);                                     \
      sB  = pkfma(KV[j+1],  XS[j+1], sB);                                     \
    }                                                                         \
    f2 dac = pkadd(daA, daB), dbc = pkadd(dbA, dbB), sc = pkadd(sA, sB);      \
    float da = halfsum(dac.x + dac.y);                                        \
    float db = halfsum(dbc.x + dbc.y);                                        \
    float sv = halfsum(sc.x + sc.y);                                          \
    float ua = BP.x * da, ub = BP.y * db;                                     \
    float aA = fmaf(ua, sv, preAa);                                           \
    float aB = fmaf(ub, sv, preAb);                                           \
    if (w == 0) {                                                             \
      if (lane < DH) *(YPTR) = aA;  /* y_T */                                 \
      float e = __expf(aB);                                                   \
      shb[(P)*72 + r] = __fdividef(e, wsum32(e));          /* q_T */          \
    } else {                                                                  \
      float e = __expf(aA);                                                   \
      shb[(P)*72 + 32 + r] = __fdividef(e, wsum32(e));     /* k_T */          \
      float sg = __fdividef(1.f, 1.f + __expf(-aB));                          \
      if (lane < 4) shb[(P)*72 + 64 + lane] = sg;          /* B_T */          \
    }                                                                         \
    BARRIER();                                                                \
    /* ---- POST: reads + register work (update, prefetch, preA) ---- */      \
    LDX4(QN, &shb[(P)*72 + c0]);                                              \
    LDX4(KN, &shb[(P)*72 + 32 + c0]);                                         \
    BPN = *(const float2*)&shb[(P)*72 + 64 + 2*w];                            \
    f2 uua = f2{ua, ua}, uub = f2{ub, ub};                                    \
    _Pragma("unroll") for (int j = 0; j < 8; ++j) {                           \
      Wa2[j] = pkfma(uua, KV[j], Wa2[j]);                                     \
      Wb2[j] = pkfma(uub, KV[j], Wb2[j]);                                     \
    }                                                                         \
    LDX4(XS, XPF);                                /* prefetch x_{T+2} */      \
    f2 paA={0.f,0.f}, paB={0.f,0.f}, pbA={0.f,0.f}, pbB={0.f,0.f};            \
    _Pragma("unroll") for (int j = 0; j < 8; j += 2) {                        \
      paA = pkfma(Wa2[j],   XP[j],   paA);                                    \
      paB = pkfma(Wa2[j+1], XP[j+1], paB);                                    \
      pbA = pkfma(Wb2[j],   XP[j],   pbA);                                    \
      pbB = pkfma(Wb2[j+1], XP[j+1], pbB);                                    \
    }                                                                         \
    f2 pac = pkadd(paA, paB), pbc = pkadd(pbA, pbB);                          \
    preAa = halfsum(pac.x + pac.y);                                           \
    preAb = halfsum(pbc.x + pbc.y);                                           \
  }

__global__ __launch_bounds__(128, 1)
void srwm_scan(const float* __restrict__ Wy0, const float* __restrict__ Wq0,
               const float* __restrict__ Wk0, const float* __restrict__ wb0,
               float* xy) {
  __align__(16) __shared__ float shb[2 * 72];  // slot P: q@0, k@32, B@64

  const int bh   = blockIdx.x;        // 0..63
  const int hd   = bh & 7;
  const int w    = threadIdx.x >> 6;  // wave: 0 (Wy,Wq) or 1 (Wk,wb^T)
  const int lane = threadIdx.x & 63;
  const int r    = lane & 31;
  const int c0   = (lane >> 5) * 16;

  const f2 mone = f2{-1.f, -1.f};

  // ---- load this wave's two matrices as f2 column-pairs ----
  f2 Wa2[8], Wb2[8];
  if (w == 0) {
    const float* pa = Wy0 + (hd * DH + r) * DH + c0;
    const float* pb = Wq0 + (hd * DH + r) * DH + c0;
    LDX4(Wa2, pa);
    LDX4(Wb2, pb);
  } else {
    const float* pa = Wk0 + (hd * DH + r) * DH + c0;
    LDX4(Wa2, pa);
    const int kk = r & 3;
#pragma unroll
    for (int j = 0; j < 8; ++j)
      Wb2[j] = f2{wb0[(hd * DH + c0 + 2*j) * 4 + kk],
                  wb0[(hd * DH + c0 + 2*j + 1) * 4 + kk]};
  }

  float* xb = xy + bh * DH;  // x/y for this (b,h): element [t*HSTRIDE + j]

  // ---- prologue: X0 <- x_0, X1 <- x_1; q_{-1}=k_{-1}=0, B_{-1}=0;
  //      preA = W_0 x_0 (u_{-1}=0) ----
  f2 X0[8], X1[8];
  LDX4(X0, xb + c0);
  LDX4(X1, xb + HSTRIDE + c0);

  float preAa, preAb;
  {
    f2 paA={0.f,0.f}, paB={0.f,0.f}, pbA={0.f,0.f}, pbB={0.f,0.f};
#pragma unroll
    for (int j = 0; j < 8; j += 2) {
      paA = pkfma(Wa2[j],   X0[j],   paA);
      paB = pkfma(Wa2[j+1], X0[j+1], paB);
      pbA = pkfma(Wb2[j],   X0[j],   pbA);
      pbB = pkfma(Wb2[j+1], X0[j+1], pbB);
    }
    f2 pac = pkadd(paA, paB), pbc = pkadd(pbA, pbB);
    preAa = halfsum(pac.x + pac.y);
    preAb = halfsum(pbc.x + pbc.y);
  }

  f2 QA[8], KA[8], QB[8], KB[8];
  const f2 z2 = f2{0.f, 0.f};
#pragma unroll
  for (int j = 0; j < 8; ++j) { QA[j] = z2; KA[j] = z2; }
  float2 BPA = {0.f, 0.f}, BPB = {0.f, 0.f};  // sigmoided betas (0 -> u=0)

  __syncthreads();

  // hot loop: strength-reduced pointers, no clamp (tail peeled)
  const float* xpf = xb + 2 * HSTRIDE + c0;  // x_{t+2} for region t
  float*       yst = xb + lane;              // y_t (w0, lane<32)

  for (int t = 0; t < SLEN - 4; t += 2) {
    REGION(0, QA, KA, BPA, QB, KB, BPB, X0, X1, xpf,           yst);
    REGION(1, QB, KB, BPB, QA, KA, BPA, X1, X0, xpf + HSTRIDE, yst + HSTRIDE);
    xpf += 2 * HSTRIDE;
    yst += 2 * HSTRIDE;
  }
  // tail: t = 1020..1023, prefetch clamped to x_{SLEN-1}
  {
    const float* xlast = xb + (size_t)(SLEN - 1) * HSTRIDE + c0;
    REGION(0, QA, KA, BPA, QB, KB, BPB, X0, X1, xlast - HSTRIDE, yst);
    REGION(1, QB, KB, BPB, QA, KA, BPA, X1, X0, xlast,           yst + HSTRIDE);
    yst += 2 * HSTRIDE;
    REGION(0, QA, KA, BPA, QB, KB, BPB, X0, X1, xlast, yst);
    REGION(1, QB, KB, BPB, QA, KA, BPA, X1, X0, xlast, yst + HSTRIDE);
  }
}

// ---------- phase 3: out = h + ys @ Wout^T  (in-place over ys==out) ----------

__global__ __launch_bounds__(256)
void srwm_proj(const float* __restrict__ h, const float* __restrict__ ys,
               const float* __restrict__ Wout, float* __restrict__ out) {
  __shared__ float ytile[32][256];  // 32 KB
  const int r0  = blockIdx.x * 32;
  const int tid = threadIdx.x;

  const float4* src = (const float4*)(ys + (size_t)r0 * 256);
  float4*       dst = (float4*)(&ytile[0][0]);
#pragma unroll
  for (int i = 0; i < 8; ++i) dst[tid + i * 256] = src[tid + i * 256];
  __syncthreads();

  float acc[32];
#pragma unroll
  for (int m = 0; m < 32; ++m) acc[m] = 0.f;

  const float* wrow = Wout + (size_t)tid * 256;
  for (int k = 0; k < 256; k += 4) {
    float4 wv = *(const float4*)(wrow + k);
#pragma unroll
    for (int m = 0; m < 32; ++m) {
      float4 y4 = *(const float4*)(&ytile[m][k]);
      acc[m] = fmaf(wv.x, y4.x,
               fmaf(wv.y, y4.y,
               fmaf(wv.z, y4.z,
               fmaf(wv.w, y4.w, acc[m]))));
    }
  }

#pragma unroll
  for (int m = 0; m < 32; ++m) {
    int row = r0 + m;
    out[(size_t)row * 256 + tid] = h[(size_t)row * 256 + tid] + acc[m];
  }
}

// ---------- launcher ----------

extern "C" void kernel_launch(void* const* d_in, const int* in_sizes, int n_in,
                              void* d_out, int out_size, void* d_ws, size_t ws_size,
                              hipStream_t stream) {
  const float* h    = (const float*)d_in[0];
  const float* Wy0  = (const float*)d_in[1];
  const float* Wq0  = (const float*)d_in[2];
  const float* Wk0  = (const float*)d_in[3];
  const float* wb0  = (const float*)d_in[4];
  const float* Wout = (const float*)d_in[5];
  float* out = (float*)d_out;

  // d_out triple duty: x (phase1) -> progressively overwritten by y (phase2)
  // -> final output (phase3, in-place via LDS tile).
  srwm_xsm <<<SLEN * HSTRIDE / 256, 256, 0, stream>>>(h, out);
  srwm_scan<<<64, 128, 0, stream>>>(Wy0, Wq0, Wk0, wb0, out);
  srwm_proj<<<256, 256, 0, stream>>>(h, out, Wout, out);
}

// Round 20
// 525.578 us; speedup vs baseline: 2.5266x; 1.0052x over previous
//
#include <hip/hip_runtime.h>

#define DEV __device__ __forceinline__

typedef float f2 __attribute__((ext_vector_type(2)));

// ---------- packed fp32 helpers (VOP3P) ----------

DEV f2 pkfma(f2 a, f2 b, f2 c) {  // c = a*b + c (acc form)
  asm("v_pk_fma_f32 %0, %1, %2, %0" : "+v"(c) : "v"(a), "v"(b));
  return c;
}
DEV f2 pkfma3(f2 a, f2 b, f2 c) {  // d = a*b + c (3-addr form)
  f2 d;
  asm("v_pk_fma_f32 %0, %1, %2, %3" : "=v"(d) : "v"(a), "v"(b), "v"(c));
  return d;
}
DEV f2 pkadd(f2 a, f2 b) {
  f2 d;
  asm("v_pk_add_f32 %0, %1, %2" : "=v"(d) : "v"(a), "v"(b));
  return d;
}

// ---------- cross-lane helpers ----------

template <int CTRL>
DEV float dppf(float x) {
  return __int_as_float(__builtin_amdgcn_update_dpp(
      0, __float_as_int(x), CTRL, 0xF, 0xF, true));
}

// Butterfly sum within each 32-lane half; result broadcast to the half.
DEV float wsum32(float v) {
  v += dppf<0xB1>(v);
  v += dppf<0x4E>(v);
  v += dppf<0x141>(v);
  v += dppf<0x140>(v);
#if __has_builtin(__builtin_amdgcn_permlane16_swap)
  {
    auto p = __builtin_amdgcn_permlane16_swap(
        __float_as_uint(v), __float_as_uint(v), false, false);
    v = __uint_as_float(p[0]) + __uint_as_float(p[1]);
  }
#else
  v += __shfl_xor(v, 16, 64);
#endif
  return v;
}

// Butterfly sum across each 8-lane group (for 4-elem/lane softmax rows).
DEV float wsum8(float v) {
  v += dppf<0xB1>(v);   // xor1
  v += dppf<0x4E>(v);   // xor2
  v += dppf<0x141>(v);  // xor4 (row_half_mirror)
  return v;
}

// v[l] + v[l^32]
DEV float halfsum(float v) {
#if __has_builtin(__builtin_amdgcn_permlane32_swap)
  auto p = __builtin_amdgcn_permlane32_swap(
      __float_as_uint(v), __float_as_uint(v), false, false);
  return __uint_as_float(p[0]) + __uint_as_float(p[1]);
#else
  return v + __shfl_xor(v, 32, 64);
#endif
}

#define SLEN 1024
#define NH 8
#define DH 32
#define HSTRIDE 2048  // floats per timestep (B*NH*DH)

// ---------- phase 1: x = softmax32(h), staged into d_out ----------
// R19 lesson (dispatch overhead): the old 8192-tiny-block version cost ~40us
// of block-dispatch throughput. Vectorized: 4 elems/thread (float4), 32-elem
// softmax group = 8 lanes -> 3-stage DPP reduce; 2048 blocks total.

__global__ __launch_bounds__(256)
void srwm_xsm4(const float* __restrict__ h, float* __restrict__ x) {
  int g = blockIdx.x * 256 + threadIdx.x;  // thread owns elements 4g..4g+3
  float4 v = *(const float4*)(h + (size_t)g * 4);
  float e0 = __expf(v.x), e1 = __expf(v.y);
  float e2 = __expf(v.z), e3 = __expf(v.w);
  float s = wsum8((e0 + e1) + (e2 + e3));  // sum over the 32-elem row
  float rs = __fdividef(1.f, s);
  float4 o = {e0 * rs, e1 * rs, e2 * rs, e3 * rs};
  *(float4*)(x + (size_t)g * 4) = o;
}

// ---------- phase 2: the scan. One block (TWO waves) per (b,h). ----------
// Wave 0 owns Wy+Wq; wave 1 owns Wk+wb^T (f2 col-pairs). Lane (r=lane&31,
// c0) holds cols c0..c0+15 of row r.  == R19 verified kernel (460us). ==
//
// Shared layout, slot P stride 72 floats: q[32]@0, k[32]@32, B[4]@64.

#define BARRIER()                                        \
  do {                                                   \
    __builtin_amdgcn_sched_barrier(0);                   \
    asm volatile("s_waitcnt lgkmcnt(0)");                \
    __builtin_amdgcn_sched_barrier(0);                   \
    __builtin_amdgcn_s_barrier();                        \
    __builtin_amdgcn_sched_barrier(0);                   \
  } while (0)

// load 16 floats at PTR directly into f2 DST[8]
#define LDX4(DST, PTR)                                                        \
  { _Pragma("unroll") for (int i_ = 0; i_ < 8; ++i_)                          \
      DST[i_] = *(const f2*)((PTR) + 2 * i_); }

#define REGION(P, QV, KV, BP, QN, KN, BPN, XS, XP, XPF, YPTR)                 \
  {                                                                           \
    /* ---- PRE: on-path compute ---- */                                      \
    f2 dv[8];                                                                 \
    _Pragma("unroll") for (int j = 0; j < 8; ++j)                             \
      dv[j] = pkfma3(KV[j], mone, QV[j]);       /* q - k */                   \
    f2 daA={0.f,0.f}, daB={0.f,0.f}, dbA={0.f,0.f}, dbB={0.f,0.f};            \
    f2 sA={0.f,0.f}, sB={0.f,0.f};                                            \
    _Pragma("unroll") for (int j = 0; j < 8; j += 2) {                        \
      daA = pkfma(Wa2[j],   dv[j],   daA);                                    \
      daB = pkfma(Wa2[j+1], dv[j+1], daB);                                    \
      dbA = pkfma(Wb2[j],   dv[j],   dbA);                                    \
      dbB = pkfma(Wb2[j+1], dv[j+1], dbB);                                    \
      sA  = pkfma(KV[j],    XS[j],   sA);                                     \
      sB  = pkfma(KV[j+1],  XS[j+1], sB);                                     \
    }                                                                         \
    f2 dac = pkadd(daA, daB), dbc = pkadd(dbA, dbB), sc = pkadd(sA, sB);      \
    float da = halfsum(dac.x + dac.y);                                        \
    float db = halfsum(dbc.x + dbc.y);                                        \
    float sv = halfsum(sc.x + sc.y);                                          \
    float ua = BP.x * da, ub = BP.y * db;                                     \
    float aA = fmaf(ua, sv, preAa);                                           \
    float aB = fmaf(ub, sv, preAb);                                           \
    if (w == 0) {                                                             \
      if (lane < DH) *(YPTR) = aA;  /* y_T */                                 \
      float e = __expf(aB);                                                   \
      shb[(P)*72 + r] = __fdividef(e, wsum32(e));          /* q_T */          \
    } else {                                                                  \
      float e = __expf(aA);                                                   \
      shb[(P)*72 + 32 + r] = __fdividef(e, wsum32(e));     /* k_T */          \
      float sg = __fdividef(1.f, 1.f + __expf(-aB));                          \
      if (lane < 4) shb[(P)*72 + 64 + lane] = sg;          /* B_T */          \
    }                                                                         \
    BARRIER();                                                                \
    /* ---- POST: reads + register work (update, prefetch, preA) ---- */      \
    LDX4(QN, &shb[(P)*72 + c0]);                                              \
    LDX4(KN, &shb[(P)*72 + 32 + c0]);                                         \
    BPN = *(const float2*)&shb[(P)*72 + 64 + 2*w];                            \
    f2 uua = f2{ua, ua}, uub = f2{ub, ub};                                    \
    _Pragma("unroll") for (int j = 0; j < 8; ++j) {                           \
      Wa2[j] = pkfma(uua, KV[j], Wa2[j]);                                     \
      Wb2[j] = pkfma(uub, KV[j], Wb2[j]);                                     \
    }                                                                         \
    LDX4(XS, XPF);                                /* prefetch x_{T+2} */      \
    f2 paA={0.f,0.f}, paB={0.f,0.f}, pbA={0.f,0.f}, pbB={0.f,0.f};            \
    _Pragma("unroll") for (int j = 0; j < 8; j += 2) {                        \
      paA = pkfma(Wa2[j],   XP[j],   paA);                                    \
      paB = pkfma(Wa2[j+1], XP[j+1], paB);                                    \
      pbA = pkfma(Wb2[j],   XP[j],   pbA);                                    \
      pbB = pkfma(Wb2[j+1], XP[j+1], pbB);                                    \
    }                                                                         \
    f2 pac = pkadd(paA, paB), pbc = pkadd(pbA, pbB);                          \
    preAa = halfsum(pac.x + pac.y);                                           \
    preAb = halfsum(pbc.x + pbc.y);                                           \
  }

__global__ __launch_bounds__(128, 1)
void srwm_scan(const float* __restrict__ Wy0, const float* __restrict__ Wq0,
               const float* __restrict__ Wk0, const float* __restrict__ wb0,
               float* xy) {
  __align__(16) __shared__ float shb[2 * 72];  // slot P: q@0, k@32, B@64

  const int bh   = blockIdx.x;        // 0..63
  const int hd   = bh & 7;
  const int w    = threadIdx.x >> 6;  // wave: 0 (Wy,Wq) or 1 (Wk,wb^T)
  const int lane = threadIdx.x & 63;
  const int r    = lane & 31;
  const int c0   = (lane >> 5) * 16;

  const f2 mone = f2{-1.f, -1.f};

  // ---- load this wave's two matrices as f2 column-pairs ----
  f2 Wa2[8], Wb2[8];
  if (w == 0) {
    const float* pa = Wy0 + (hd * DH + r) * DH + c0;
    const float* pb = Wq0 + (hd * DH + r) * DH + c0;
    LDX4(Wa2, pa);
    LDX4(Wb2, pb);
  } else {
    const float* pa = Wk0 + (hd * DH + r) * DH + c0;
    LDX4(Wa2, pa);
    const int kk = r & 3;
#pragma unroll
    for (int j = 0; j < 8; ++j)
      Wb2[j] = f2{wb0[(hd * DH + c0 + 2*j) * 4 + kk],
                  wb0[(hd * DH + c0 + 2*j + 1) * 4 + kk]};
  }

  float* xb = xy + bh * DH;  // x/y for this (b,h): element [t*HSTRIDE + j]

  // ---- prologue: X0 <- x_0, X1 <- x_1; q_{-1}=k_{-1}=0, B_{-1}=0;
  //      preA = W_0 x_0 (u_{-1}=0) ----
  f2 X0[8], X1[8];
  LDX4(X0, xb + c0);
  LDX4(X1, xb + HSTRIDE + c0);

  float preAa, preAb;
  {
    f2 paA={0.f,0.f}, paB={0.f,0.f}, pbA={0.f,0.f}, pbB={0.f,0.f};
#pragma unroll
    for (int j = 0; j < 8; j += 2) {
      paA = pkfma(Wa2[j],   X0[j],   paA);
      paB = pkfma(Wa2[j+1], X0[j+1], paB);
      pbA = pkfma(Wb2[j],   X0[j],   pbA);
      pbB = pkfma(Wb2[j+1], X0[j+1], pbB);
    }
    f2 pac = pkadd(paA, paB), pbc = pkadd(pbA, pbB);
    preAa = halfsum(pac.x + pac.y);
    preAb = halfsum(pbc.x + pbc.y);
  }

  f2 QA[8], KA[8], QB[8], KB[8];
  const f2 z2 = f2{0.f, 0.f};
#pragma unroll
  for (int j = 0; j < 8; ++j) { QA[j] = z2; KA[j] = z2; }
  float2 BPA = {0.f, 0.f}, BPB = {0.f, 0.f};  // sigmoided betas (0 -> u=0)

  __syncthreads();

  // hot loop: strength-reduced pointers, no clamp (tail peeled)
  const float* xpf = xb + 2 * HSTRIDE + c0;  // x_{t+2} for region t
  float*       yst = xb + lane;              // y_t (w0, lane<32)

  for (int t = 0; t < SLEN - 4; t += 2) {
    REGION(0, QA, KA, BPA, QB, KB, BPB, X0, X1, xpf,           yst);
    REGION(1, QB, KB, BPB, QA, KA, BPA, X1, X0, xpf + HSTRIDE, yst + HSTRIDE);
    xpf += 2 * HSTRIDE;
    yst += 2 * HSTRIDE;
  }
  // tail: t = 1020..1023, prefetch clamped to x_{SLEN-1}
  {
    const float* xlast = xb + (size_t)(SLEN - 1) * HSTRIDE + c0;
    REGION(0, QA, KA, BPA, QB, KB, BPB, X0, X1, xlast - HSTRIDE, yst);
    REGION(1, QB, KB, BPB, QA, KA, BPA, X1, X0, xlast,           yst + HSTRIDE);
    yst += 2 * HSTRIDE;
    REGION(0, QA, KA, BPA, QB, KB, BPB, X0, X1, xlast, yst);
    REGION(1, QB, KB, BPB, QA, KA, BPA, X1, X0, xlast, yst + HSTRIDE);
  }
}

// ---------- phase 3: out = h + ys @ Wout^T  (in-place over ys==out) ----------

__global__ __launch_bounds__(256)
void srwm_proj(const float* __restrict__ h, const float* __restrict__ ys,
               const float* __restrict__ Wout, float* __restrict__ out) {
  __shared__ float ytile[32][256];  // 32 KB
  const int r0  = blockIdx.x * 32;
  const int tid = threadIdx.x;

  const float4* src = (const float4*)(ys + (size_t)r0 * 256);
  float4*       dst = (float4*)(&ytile[0][0]);
#pragma unroll
  for (int i = 0; i < 8; ++i) dst[tid + i * 256] = src[tid + i * 256];
  __syncthreads();

  float acc[32];
#pragma unroll
  for (int m = 0; m < 32; ++m) acc[m] = 0.f;

  const float* wrow = Wout + (size_t)tid * 256;
  for (int k = 0; k < 256; k += 4) {
    float4 wv = *(const float4*)(wrow + k);
#pragma unroll
    for (int m = 0; m < 32; ++m) {
      float4 y4 = *(const float4*)(&ytile[m][k]);
      acc[m] = fmaf(wv.x, y4.x,
               fmaf(wv.y, y4.y,
               fmaf(wv.z, y4.z,
               fmaf(wv.w, y4.w, acc[m]))));
    }
  }

#pragma unroll
  for (int m = 0; m < 32; ++m) {
    int row = r0 + m;
    out[(size_t)row * 256 + tid] = h[(size_t)row * 256 + tid] + acc[m];
  }
}

// ---------- launcher ----------

extern "C" void kernel_launch(void* const* d_in, const int* in_sizes, int n_in,
                              void* d_out, int out_size, void* d_ws, size_t ws_size,
                              hipStream_t stream) {
  const float* h    = (const float*)d_in[0];
  const float* Wy0  = (const float*)d_in[1];
  const float* Wq0  = (const float*)d_in[2];
  const float* Wk0  = (const float*)d_in[3];
  const float* wb0  = (const float*)d_in[4];
  const float* Wout = (const float*)d_in[5];
  float* out = (float*)d_out;

  // d_out triple duty: x (phase1) -> progressively overwritten by y (phase2)
  // -> final output (phase3, in-place via LDS tile).
  srwm_xsm4<<<SLEN * HSTRIDE / 1024, 256, 0, stream>>>(h, out);
  srwm_scan<<<64, 128, 0, stream>>>(Wy0, Wq0, Wk0, wb0, out);
  srwm_proj<<<256, 256, 0, stream>>>(h, out, Wout, out);
}